// Round 1
// baseline (194.662 us; speedup 1.0000x reference)
//
#include <hip/hip_runtime.h>
#include <math.h>

#define N_NODES 650
#define DIM     512
#define E_RAW   150000
#define E_TOT   150650
#define WK      672              // padded K for dense attention matrix (21*32, 16B-aligned rows)
#define ZG      8                // split-K for feature GEMMs: K=512, KC=64
#define ZA      6                // split-K for agg GEMMs:     K=672, KC=112

// =============== 64x64 split-K GEMM, 4x4 per-thread micro-tile ===============
// P[z] = A[:, z*kc:(z+1)*kc] @ B[z*kc:(z+1)*kc, :]   (N fixed at 512)
// a_mode 1: rows <400 from A (x_s), rows >=400 from Axt (x_t); a_mode 0: plain A, stride lda
__global__ __launch_bounds__(256)
void gemm4(const float* __restrict__ A, const float* __restrict__ Axt,
           const float* __restrict__ B, float* __restrict__ P,
           int M, int lda, int ldb, int kc, int a_mode) {
    __shared__ float Ast[16][68];   // transposed A tile, stride 68 (16B-aligned, 2-way banks)
    __shared__ float Bs[16][64];
    int t = threadIdx.x;
    int tx4 = (t & 15) * 4, ty4 = (t >> 4) * 4;
    int row0 = blockIdx.y * 64, col0 = blockIdx.x * 64;
    int kbase = blockIdx.z * kc;
    int ar = t >> 2, ak = (t & 3) * 4;     // A staging: 64 rows x 16 k, one float4/thread
    int bk = t >> 4, bn = (t & 15) * 4;    // B staging: 16 k x 64 cols, one float4/thread
    float acc[4][4] = {};

    for (int kb = kbase; kb < kbase + kc; kb += 16) {
        {   // stage A, transposed into LDS
            int gr = row0 + ar;
            float4 v = make_float4(0.f, 0.f, 0.f, 0.f);
            if (gr < M) {
                const float* rowp;
                if (a_mode == 1)
                    rowp = (gr < 400) ? (A + (size_t)gr * lda) : (Axt + (size_t)(gr - 400) * lda);
                else
                    rowp = A + (size_t)gr * lda;
                v = *(const float4*)(rowp + kb + ak);
            }
            Ast[ak + 0][ar] = v.x; Ast[ak + 1][ar] = v.y;
            Ast[ak + 2][ar] = v.z; Ast[ak + 3][ar] = v.w;
        }
        // stage B
        *(float4*)&Bs[bk][bn] = *(const float4*)&B[(size_t)(kb + bk) * ldb + col0 + bn];
        __syncthreads();
        #pragma unroll
        for (int kk = 0; kk < 16; kk++) {
            float4 a = *(const float4*)&Ast[kk][ty4];
            float4 b = *(const float4*)&Bs[kk][tx4];
            acc[0][0] += a.x*b.x; acc[0][1] += a.x*b.y; acc[0][2] += a.x*b.z; acc[0][3] += a.x*b.w;
            acc[1][0] += a.y*b.x; acc[1][1] += a.y*b.y; acc[1][2] += a.y*b.z; acc[1][3] += a.y*b.w;
            acc[2][0] += a.z*b.x; acc[2][1] += a.z*b.y; acc[2][2] += a.z*b.z; acc[2][3] += a.z*b.w;
            acc[3][0] += a.w*b.x; acc[3][1] += a.w*b.y; acc[3][2] += a.w*b.z; acc[3][3] += a.w*b.w;
        }
        __syncthreads();
    }

    float* Cout = P + (size_t)blockIdx.z * (N_NODES * DIM);
    #pragma unroll
    for (int i = 0; i < 4; i++) {
        int gr = row0 + ty4 + i;
        if (gr < M)
            *(float4*)&Cout[(size_t)gr * DIM + col0 + tx4] =
                make_float4(acc[i][0], acc[i][1], acc[i][2], acc[i][3]);
    }
}

// =============== reduce split-K partials (z=ZG) + per-row attention logits ===============
__global__ __launch_bounds__(256)
void reduce_logits(const float* __restrict__ P,
                   const float* __restrict__ asrc, const float* __restrict__ adst,
                   float* __restrict__ h, float* __restrict__ als, float* __restrict__ ald) {
    __shared__ float red[8];
    const size_t S = (size_t)N_NODES * DIM;
    int r = blockIdx.x, t = threadIdx.x;
    size_t base = (size_t)r * DIM;
    float v0 = 0.f, v1 = 0.f;
    #pragma unroll
    for (int z = 0; z < ZG; z++) {
        v0 += P[z * S + base + t];
        v1 += P[z * S + base + t + 256];
    }
    h[base + t]       = v0;
    h[base + t + 256] = v1;
    float ps = v0 * asrc[t] + v1 * asrc[t + 256];
    float pd = v0 * adst[t] + v1 * adst[t + 256];
    #pragma unroll
    for (int o = 32; o > 0; o >>= 1) {
        ps += __shfl_down(ps, o);
        pd += __shfl_down(pd, o);
    }
    if ((t & 63) == 0) { red[t >> 6] = ps; red[4 + (t >> 6)] = pd; }
    __syncthreads();
    if (t == 0) als[r] = red[0] + red[1] + red[2] + red[3];
    if (t == 1) ald[r] = red[4] + red[5] + red[6] + red[7];
}

// =============== dense attention-matrix build from raw edge list ===============
// W[d][s] += exp(leaky(als[s]+ald[d])), rowsum via per-block LDS binning.
// W and rs must be zeroed beforehand (one upfront memset).
__global__ __launch_bounds__(256)
void build_w(const int* __restrict__ ei, const float* __restrict__ als,
             const float* __restrict__ ald, float* __restrict__ W,
             float* __restrict__ rs) {
    __shared__ float lrs[N_NODES];
    for (int l = threadIdx.x; l < N_NODES; l += 256) lrs[l] = 0.f;
    __syncthreads();
    int stride = gridDim.x * 256;
    for (int i = blockIdx.x * 256 + threadIdx.x; i < E_TOT; i += stride) {
        int s, d;
        if (i < E_RAW) { s = ei[i]; d = ei[E_RAW + i]; }
        else           { s = d = i - E_RAW; }
        float e = als[s] + ald[d];
        e = e > 0.f ? e : 0.2f * e;
        float ex = __expf(e);
        atomicAdd(&W[(size_t)d * WK + s], ex);
        atomicAdd(&lrs[d], ex);
    }
    __syncthreads();
    for (int l = threadIdx.x; l < N_NODES; l += 256)
        if (lrs[l] != 0.f) atomicAdd(&rs[l], lrs[l]);
}

// =============== reduce agg partials (z=ZA), normalize, bias, activation ===============
__global__ __launch_bounds__(256)
void aggred(const float* __restrict__ P, const float* __restrict__ rs,
            const float* __restrict__ bias, float slope, float* __restrict__ o) {
    const size_t S = (size_t)N_NODES * DIM;
    int r = blockIdx.x, t = threadIdx.x;
    size_t base = (size_t)r * DIM;
    float v0 = 0.f, v1 = 0.f;
    #pragma unroll
    for (int z = 0; z < ZA; z++) {
        v0 += P[z * S + base + t];
        v1 += P[z * S + base + t + 256];
    }
    float inv = 1.f / (rs[r] + 1e-16f);
    float a = v0 * inv + bias[t];
    float b = v1 * inv + bias[t + 256];
    o[base + t]       = a > 0.f ? a : slope * a;
    o[base + t + 256] = b > 0.f ? b : slope * b;
}

// =============== final: reshape(512,650) @ fc_w + fc_b -> sigmoid ===============
__global__ void final_kernel(const float* __restrict__ o2,
                             const float* __restrict__ fcw,
                             const float* __restrict__ fcb,
                             float* __restrict__ out) {
    int b = blockIdx.x * 4 + (threadIdx.x >> 6);
    int lane = threadIdx.x & 63;
    if (b >= 512) return;
    float s = 0.f;
    for (int i = lane; i < N_NODES; i += 64)
        s += o2[b * N_NODES + i] * fcw[i];
    #pragma unroll
    for (int o = 32; o > 0; o >>= 1) s += __shfl_down(s, o);
    if (lane == 0) out[b] = 1.f / (1.f + expf(-(s + fcb[0])));
}

extern "C" void kernel_launch(void* const* d_in, const int* in_sizes, int n_in,
                              void* d_out, int out_size, void* d_ws, size_t ws_size,
                              hipStream_t stream) {
    const float* x_s   = (const float*)d_in[0];
    const float* x_t   = (const float*)d_in[1];
    const int*   ei    = (const int*)d_in[2];
    const float* W1    = (const float*)d_in[5];
    const float* asrc1 = (const float*)d_in[6];
    const float* adst1 = (const float*)d_in[7];
    const float* b1    = (const float*)d_in[8];
    const float* W4    = (const float*)d_in[9];
    const float* asrc4 = (const float*)d_in[10];
    const float* adst4 = (const float*)d_in[11];
    const float* b4    = (const float*)d_in[12];
    const float* fcw   = (const float*)d_in[13];
    const float* fcb   = (const float*)d_in[14];
    float* out = (float*)d_out;

    const size_t S = (size_t)N_NODES * DIM;         // 332800
    float* ws   = (float*)d_ws;
    float* als1 = ws;                               // 650
    float* ald1 = als1 + N_NODES;                   // 650
    float* als2 = ald1 + N_NODES;                   // 650
    float* ald2 = als2 + N_NODES;                   // 650
    float* P    = ald2 + N_NODES;                   // ZG * S = 2,662,400
    float* o1   = P + (size_t)ZG * S;               // 332800
    float* o2   = o1 + S;                           // 332800
    float* h    = o2 + S;                           // WK*512 = 344064 (rows 650..671 stay zero)
    float* W1d  = h + (size_t)WK * DIM;             // 650*672
    float* W2d  = W1d + (size_t)N_NODES * WK;       // 650*672
    float* rs1  = W2d + (size_t)N_NODES * WK;       // 650
    float* rs2  = rs1 + N_NODES;                    // 650

    // one contiguous zero region: h pad rows (650..671) + W1d + W2d + rs1 + rs2
    float* zbeg = h + (size_t)N_NODES * DIM;
    size_t zbytes = (size_t)((WK - N_NODES) * DIM           // h padding rows
                           + 2 * N_NODES * WK               // W1d, W2d
                           + 2 * N_NODES) * sizeof(float);  // rs1, rs2
    hipMemsetAsync(zbeg, 0, zbytes, stream);

    dim3 gG(DIM / 64, (N_NODES + 63) / 64, ZG);     // 8 x 11 x 8 = 704 blocks
    dim3 gA(DIM / 64, (N_NODES + 63) / 64, ZA);     // 8 x 11 x 6 = 528 blocks

    // ---- layer 1 ----
    gemm4<<<gG, 256, 0, stream>>>(x_s, x_t, W1, P, N_NODES, DIM, DIM, 64, 1);
    reduce_logits<<<N_NODES, 256, 0, stream>>>(P, asrc1, adst1, h, als1, ald1);
    build_w<<<128, 256, 0, stream>>>(ei, als1, ald1, W1d, rs1);
    gemm4<<<gA, 256, 0, stream>>>(W1d, nullptr, h, P, N_NODES, WK, DIM, 112, 0);
    aggred<<<N_NODES, 256, 0, stream>>>(P, rs1, b1, 0.0f, o1);

    // ---- layer 2 ----
    gemm4<<<gG, 256, 0, stream>>>(o1, nullptr, W4, P, N_NODES, DIM, DIM, 64, 0);
    reduce_logits<<<N_NODES, 256, 0, stream>>>(P, asrc4, adst4, h, als2, ald2);
    build_w<<<128, 256, 0, stream>>>(ei, als2, ald2, W2d, rs2);
    gemm4<<<gA, 256, 0, stream>>>(W2d, nullptr, h, P, N_NODES, WK, DIM, 112, 0);
    aggred<<<N_NODES, 256, 0, stream>>>(P, rs2, b4, 0.01f, o2);

    // ---- final ----
    final_kernel<<<128, 256, 0, stream>>>(o2, fcw, fcb, out);
}